// Round 1
// baseline (1276.206 us; speedup 1.0000x reference)
//
#include <hip/hip_runtime.h>
#include <hip/hip_bf16.h>

// GCN: 4 layers. N=100000 nodes, E=1600000 edges, F=128, H=128, C=40. fp32.
// Pipeline per call:
//   1. counts[i]=1 (self-loop), cursor[i]=0
//   2. atomic count of dst -> counts
//   3. dinv[i] = 1/sqrt(counts[i])
//   4. exclusive scan of (counts[i]-1) -> CSR offsets (single 1024-thread block)
//   5. scatter edges into srcSorted by dst bucket (atomic cursor)
//   6. per layer: tiled fp32 GEMM, then atomic-free CSR aggregation
//      out_i = dinv[i] * (dinv[i]*h[i] + sum_s dinv[s]*h[s]) + b  (+relu layers 1-3)
// ws layout: counts,cursor,offsets,dinv,srcSorted, hA[N*128], hB[N*128]  (~111 MB)

#define N_NODES 100000
#define N_EDGES 1600000

// ---------------- CSR build ----------------

__global__ void init_counts(int* counts, int* cursor, int n) {
    int i = blockIdx.x * blockDim.x + threadIdx.x;
    if (i < n) { counts[i] = 1; cursor[i] = 0; }
}

__global__ void count_edges(const int* __restrict__ dst, int* __restrict__ counts, int e) {
    int i = blockIdx.x * blockDim.x + threadIdx.x;
    if (i < e) atomicAdd(&counts[dst[i]], 1);
}

__global__ void compute_dinv(const int* __restrict__ counts, float* __restrict__ dinv, int n) {
    int i = blockIdx.x * blockDim.x + threadIdx.x;
    if (i < n) dinv[i] = 1.0f / sqrtf((float)counts[i]);
}

__global__ __launch_bounds__(1024) void scan_offsets(const int* __restrict__ counts,
                                                     int* __restrict__ offsets, int n) {
    __shared__ int sums[1024];
    int t = threadIdx.x;
    int ch = (n + 1023) >> 10;
    int beg = t * ch;
    int end = beg + ch; if (end > n) end = n;
    int s = 0;
    for (int j = beg; j < end; j++) s += counts[j] - 1;   // CSR holds real edges only
    sums[t] = s;
    __syncthreads();
    for (int off = 1; off < 1024; off <<= 1) {
        int v = (t >= off) ? sums[t - off] : 0;
        __syncthreads();
        sums[t] += v;
        __syncthreads();
    }
    int base = (t == 0) ? 0 : sums[t - 1];
    for (int j = beg; j < end; j++) { offsets[j] = base; base += counts[j] - 1; }
    if (t == 1023) offsets[n] = sums[1023];
}

__global__ void scatter_edges(const int* __restrict__ src, const int* __restrict__ dst,
                              const int* __restrict__ offsets, int* __restrict__ cursor,
                              int* __restrict__ srcSorted, int e) {
    int i = blockIdx.x * blockDim.x + threadIdx.x;
    if (i < e) {
        int d = dst[i];
        int pos = offsets[d] + atomicAdd(&cursor[d], 1);
        srcSorted[pos] = src[i];
    }
}

// ---------------- GEMM: [M,128] @ [128,128] -> [M,128], fp32 vector ----------------
// BM=128, BN=128, BK=8, 256 threads, 8x8 microtile.

__global__ __launch_bounds__(256) void gemm_f32_128(const float* __restrict__ A,
                                                    const float* __restrict__ B,
                                                    float* __restrict__ C, int M) {
    __shared__ float As[8][132];   // transposed tile: As[k][m], +4 pad
    __shared__ float Bs[8][128];   // Bs[k][n]
    int t = threadIdx.x;
    int block_row = blockIdx.x * 128;

    int aRow = t >> 1;          // 0..127
    int aK   = (t & 1) * 4;     // 0 or 4
    int bK   = t >> 5;          // 0..7
    int bCol = (t & 31) * 4;    // 0..124
    int tr = (t >> 4) * 8;      // 0..120
    int tc = (t & 15) * 8;      // 0..120

    float acc[8][8];
#pragma unroll
    for (int i = 0; i < 8; i++)
#pragma unroll
        for (int j = 0; j < 8; j++) acc[i][j] = 0.0f;

    int gRowA = block_row + aRow; if (gRowA >= M) gRowA = M - 1;   // clamp; store guarded
    const float* Aptr = A + (size_t)gRowA * 128 + aK;

    for (int k0 = 0; k0 < 128; k0 += 8) {
        float4 av = *(const float4*)(Aptr + k0);
        float4 bv = *(const float4*)(B + (size_t)(k0 + bK) * 128 + bCol);
        __syncthreads();
        As[aK + 0][aRow] = av.x;
        As[aK + 1][aRow] = av.y;
        As[aK + 2][aRow] = av.z;
        As[aK + 3][aRow] = av.w;
        *(float4*)&Bs[bK][bCol] = bv;
        __syncthreads();
#pragma unroll
        for (int k = 0; k < 8; k++) {
            float am[8], bn[8];
            *(float4*)&am[0] = *(const float4*)&As[k][tr];
            *(float4*)&am[4] = *(const float4*)&As[k][tr + 4];
            *(float4*)&bn[0] = *(const float4*)&Bs[k][tc];
            *(float4*)&bn[4] = *(const float4*)&Bs[k][tc + 4];
#pragma unroll
            for (int i = 0; i < 8; i++)
#pragma unroll
                for (int j = 0; j < 8; j++) acc[i][j] += am[i] * bn[j];
        }
    }

#pragma unroll
    for (int i = 0; i < 8; i++) {
        int gr = block_row + tr + i;
        if (gr < M) {
#pragma unroll
            for (int j = 0; j < 8; j += 4) {
                float4 v = make_float4(acc[i][j], acc[i][j+1], acc[i][j+2], acc[i][j+3]);
                *(float4*)(C + (size_t)gr * 128 + tc + j) = v;
            }
        }
    }
}

// ---------------- GEMM: [M,128] @ [128,40] -> [M,40] ----------------
// 320 threads, 32 rows/block; thread -> (r = t/10, 4 cols at (t%10)*4)

__global__ __launch_bounds__(320) void gemm_f32_40(const float* __restrict__ A,
                                                   const float* __restrict__ B,
                                                   float* __restrict__ C, int M) {
    __shared__ float Ws[128][40];   // 20 KB, no pad (40%4==0 keeps float4 align)
    __shared__ float Xs[32][132];   // padded rows
    int t = threadIdx.x;
    int block_row = blockIdx.x * 32;

    for (int i = t; i < 128 * 40; i += 320) ((float*)Ws)[i] = B[i];
    for (int idx = t; idx < 1024; idx += 320) {
        int row = idx >> 5;
        int k4  = (idx & 31) << 2;
        int gr = block_row + row; if (gr >= M) gr = M - 1;
        float4 v = *(const float4*)(A + (size_t)gr * 128 + k4);
        *(float4*)&Xs[row][k4] = v;
    }
    __syncthreads();

    int r  = t / 10;          // 0..31
    int c0 = (t % 10) * 4;    // 0..36
    float4 acc = make_float4(0.f, 0.f, 0.f, 0.f);
    for (int k = 0; k < 128; k += 4) {
        float4 xv = *(const float4*)&Xs[r][k];
#pragma unroll
        for (int j = 0; j < 4; j++) {
            float xj = (j == 0) ? xv.x : (j == 1) ? xv.y : (j == 2) ? xv.z : xv.w;
            float4 wv = *(const float4*)&Ws[k + j][c0];
            acc.x += xj * wv.x; acc.y += xj * wv.y;
            acc.z += xj * wv.z; acc.w += xj * wv.w;
        }
    }
    int gr = block_row + r;
    if (gr < M) *(float4*)(C + (size_t)gr * 40 + c0) = acc;
}

// ---------------- CSR aggregation (atomic-free): one wave per node ----------------
// out[i] = relu?( dinv[i] * (dinv[i]*h[i] + sum_s dinv[s]*h[s]) + b )

template <int NF, bool RELU>
__global__ __launch_bounds__(256) void agg_kernel(const float* __restrict__ h,
                                                  const float* __restrict__ dinv,
                                                  const int* __restrict__ offsets,
                                                  const int* __restrict__ srcSorted,
                                                  const float* __restrict__ bias,
                                                  float* __restrict__ out, int n) {
    int wave = threadIdx.x >> 6;
    int lane = threadIdx.x & 63;
    int node = blockIdx.x * 4 + wave;
    if (node >= n) return;

    float di = dinv[node];
    int f = lane * 2;
    float2 acc = make_float2(0.f, 0.f);
    if (f < NF) {
        float2 hv = *(const float2*)(h + (size_t)node * NF + f);
        acc.x = di * hv.x; acc.y = di * hv.y;
    }
    int beg = offsets[node], end = offsets[node + 1];
    for (int idx = beg; idx < end; idx++) {
        int s = srcSorted[idx];
        float w = dinv[s];
        if (f < NF) {
            float2 hv = *(const float2*)(h + (size_t)s * NF + f);
            acc.x += w * hv.x; acc.y += w * hv.y;
        }
    }
    if (f < NF) {
        float2 o;
        o.x = di * acc.x + bias[f];
        o.y = di * acc.y + bias[f + 1];
        if (RELU) { o.x = fmaxf(o.x, 0.f); o.y = fmaxf(o.y, 0.f); }
        *(float2*)(out + (size_t)node * NF + f) = o;
    }
}

// ---------------- orchestration ----------------

extern "C" void kernel_launch(void* const* d_in, const int* in_sizes, int n_in,
                              void* d_out, int out_size, void* d_ws, size_t ws_size,
                              hipStream_t stream) {
    const float* x  = (const float*)d_in[0];
    const int* edge = (const int*)d_in[1];
    const float* W1 = (const float*)d_in[2]; const float* b1 = (const float*)d_in[3];
    const float* W2 = (const float*)d_in[4]; const float* b2 = (const float*)d_in[5];
    const float* W3 = (const float*)d_in[6]; const float* b3 = (const float*)d_in[7];
    const float* W4 = (const float*)d_in[8]; const float* b4 = (const float*)d_in[9];

    const int N = in_sizes[0] / 128;      // 100000
    const int E = in_sizes[1] / 2;        // 1600000
    const int* src = edge;
    const int* dst = edge + E;

    float* out_final = (float*)d_out;                    // [N,40]
    float* x_latent  = (float*)d_out + (size_t)N * 40;   // [N,128]

    // workspace carve-up (~111 MB)
    char* w = (char*)d_ws;
    int* counts    = (int*)w;  w += (size_t)N * 4;
    int* cursor    = (int*)w;  w += (size_t)N * 4;
    int* offsets   = (int*)w;  w += (size_t)(N + 4) * 4;
    float* dinv    = (float*)w; w += (size_t)N * 4;
    int* srcSorted = (int*)w;  w += (size_t)E * 4;
    w = (char*)(((uintptr_t)w + 255) & ~(uintptr_t)255);
    float* hA = (float*)w; w += (size_t)N * 128 * 4;
    float* hB = (float*)w; w += (size_t)N * 128 * 4;

    int gN = (N + 255) / 256;
    int gE = (E + 255) / 256;

    init_counts<<<gN, 256, 0, stream>>>(counts, cursor, N);
    count_edges<<<gE, 256, 0, stream>>>(dst, counts, E);
    compute_dinv<<<gN, 256, 0, stream>>>(counts, dinv, N);
    scan_offsets<<<1, 1024, 0, stream>>>(counts, offsets, N);
    scatter_edges<<<gE, 256, 0, stream>>>(src, dst, offsets, cursor, srcSorted, E);

    int gGemm = (N + 127) / 128;   // 782
    int gAgg  = (N + 3) / 4;       // 25000

    // layer 1: x -> hA -> hB
    gemm_f32_128<<<gGemm, 256, 0, stream>>>(x, W1, hA, N);
    agg_kernel<128, true><<<gAgg, 256, 0, stream>>>(hA, dinv, offsets, srcSorted, b1, hB, N);
    // layer 2: hB -> hA -> hB  (gemm out hA, agg out back to hB... use hA->hB then swap)
    gemm_f32_128<<<gGemm, 256, 0, stream>>>(hB, W2, hA, N);
    agg_kernel<128, true><<<gAgg, 256, 0, stream>>>(hA, dinv, offsets, srcSorted, b2, hB, N);
    // layer 3: hB -> hA -> x_latent
    gemm_f32_128<<<gGemm, 256, 0, stream>>>(hB, W3, hA, N);
    agg_kernel<128, true><<<gAgg, 256, 0, stream>>>(hA, dinv, offsets, srcSorted, b3, x_latent, N);
    // layer 4: x_latent -> hA[:,0:40] -> out_final (no relu)
    gemm_f32_40<<<(N + 31) / 32, 320, 0, stream>>>(x_latent, W4, hA, N);
    agg_kernel<40, false><<<gAgg, 256, 0, stream>>>(hA, dinv, offsets, srcSorted, b4, out_final, N);
}

// Round 2
// 907.600 us; speedup vs baseline: 1.4061x; 1.4061x over previous
//
#include <hip/hip_runtime.h>
#include <hip/hip_bf16.h>

// GCN: 4 layers. N=100000 nodes, E=1600000 edges, F=128, H=128, C=40. fp32.
// R1 changes vs R0:
//  - agg_kernel: 4-way unrolled neighbor loop, 4 independent accumulators (MLP)
//  - scan_offsets replaced by 3-kernel hierarchical scan (coalesced, multi-CU)

#define N_NODES 100000
#define N_EDGES 1600000

// ---------------- CSR build ----------------

__global__ void init_counts(int* counts, int* cursor, int n) {
    int i = blockIdx.x * blockDim.x + threadIdx.x;
    if (i < n) { counts[i] = 1; cursor[i] = 0; }
}

__global__ void count_edges(const int* __restrict__ dst, int* __restrict__ counts, int e) {
    int i = blockIdx.x * blockDim.x + threadIdx.x;
    if (i < e) atomicAdd(&counts[dst[i]], 1);
}

__global__ void compute_dinv(const int* __restrict__ counts, float* __restrict__ dinv, int n) {
    int i = blockIdx.x * blockDim.x + threadIdx.x;
    if (i < n) dinv[i] = 1.0f / sqrtf((float)counts[i]);
}

// Hierarchical exclusive scan of (counts[i]-1) -> offsets[0..n], offsets[n]=E.
// phase1: per-block (1024 elems) totals. phase2: 1-block scan of block totals.
// phase3: per-block local scan + global prefix -> offsets.

__global__ __launch_bounds__(256) void scan_phase1(const int* __restrict__ counts,
                                                   int* __restrict__ blockSums, int n) {
    __shared__ int red[256];
    int t = threadIdx.x;
    int base = blockIdx.x * 1024 + t * 4;
    int s = 0;
    if (base + 3 < n) {
        int4 v = *(const int4*)(counts + base);
        s = v.x + v.y + v.z + v.w - 4;
    } else {
        for (int j = 0; j < 4; j++) if (base + j < n) s += counts[base + j] - 1;
    }
    red[t] = s;
    __syncthreads();
    for (int off = 128; off > 0; off >>= 1) {
        if (t < off) red[t] += red[t + off];
        __syncthreads();
    }
    if (t == 0) blockSums[blockIdx.x] = red[0];
}

__global__ __launch_bounds__(1024) void scan_phase2(int* __restrict__ blockSums, int nb) {
    __shared__ int sh[1024];
    int t = threadIdx.x;
    sh[t] = (t < nb) ? blockSums[t] : 0;
    __syncthreads();
    for (int off = 1; off < 1024; off <<= 1) {
        int v = (t >= off) ? sh[t - off] : 0;
        __syncthreads();
        sh[t] += v;
        __syncthreads();
    }
    if (t < nb) blockSums[t] = (t == 0) ? 0 : sh[t - 1];   // exclusive
}

__global__ __launch_bounds__(256) void scan_phase3(const int* __restrict__ counts,
                                                   const int* __restrict__ blockSums,
                                                   int* __restrict__ offsets, int n, int total) {
    __shared__ int red[256];
    int t = threadIdx.x;
    int base = blockIdx.x * 1024 + t * 4;
    int c[4];
#pragma unroll
    for (int j = 0; j < 4; j++) c[j] = (base + j < n) ? counts[base + j] - 1 : 0;
    int s = c[0] + c[1] + c[2] + c[3];
    red[t] = s;
    __syncthreads();
    for (int off = 1; off < 256; off <<= 1) {
        int v = (t >= off) ? red[t - off] : 0;
        __syncthreads();
        red[t] += v;
        __syncthreads();
    }
    int prefix = blockSums[blockIdx.x] + ((t == 0) ? 0 : red[t - 1]);
#pragma unroll
    for (int j = 0; j < 4; j++) {
        if (base + j < n) offsets[base + j] = prefix;
        prefix += c[j];
    }
    if (blockIdx.x == 0 && t == 0) offsets[n] = total;
}

__global__ void scatter_edges(const int* __restrict__ src, const int* __restrict__ dst,
                              const int* __restrict__ offsets, int* __restrict__ cursor,
                              int* __restrict__ srcSorted, int e) {
    int i = blockIdx.x * blockDim.x + threadIdx.x;
    if (i < e) {
        int d = dst[i];
        int pos = offsets[d] + atomicAdd(&cursor[d], 1);
        srcSorted[pos] = src[i];
    }
}

// ---------------- GEMM: [M,128] @ [128,128] -> [M,128], fp32 vector ----------------

__global__ __launch_bounds__(256) void gemm_f32_128(const float* __restrict__ A,
                                                    const float* __restrict__ B,
                                                    float* __restrict__ C, int M) {
    __shared__ float As[8][132];
    __shared__ float Bs[8][128];
    int t = threadIdx.x;
    int block_row = blockIdx.x * 128;

    int aRow = t >> 1;
    int aK   = (t & 1) * 4;
    int bK   = t >> 5;
    int bCol = (t & 31) * 4;
    int tr = (t >> 4) * 8;
    int tc = (t & 15) * 8;

    float acc[8][8];
#pragma unroll
    for (int i = 0; i < 8; i++)
#pragma unroll
        for (int j = 0; j < 8; j++) acc[i][j] = 0.0f;

    int gRowA = block_row + aRow; if (gRowA >= M) gRowA = M - 1;
    const float* Aptr = A + (size_t)gRowA * 128 + aK;

    for (int k0 = 0; k0 < 128; k0 += 8) {
        float4 av = *(const float4*)(Aptr + k0);
        float4 bv = *(const float4*)(B + (size_t)(k0 + bK) * 128 + bCol);
        __syncthreads();
        As[aK + 0][aRow] = av.x;
        As[aK + 1][aRow] = av.y;
        As[aK + 2][aRow] = av.z;
        As[aK + 3][aRow] = av.w;
        *(float4*)&Bs[bK][bCol] = bv;
        __syncthreads();
#pragma unroll
        for (int k = 0; k < 8; k++) {
            float am[8], bn[8];
            *(float4*)&am[0] = *(const float4*)&As[k][tr];
            *(float4*)&am[4] = *(const float4*)&As[k][tr + 4];
            *(float4*)&bn[0] = *(const float4*)&Bs[k][tc];
            *(float4*)&bn[4] = *(const float4*)&Bs[k][tc + 4];
#pragma unroll
            for (int i = 0; i < 8; i++)
#pragma unroll
                for (int j = 0; j < 8; j++) acc[i][j] += am[i] * bn[j];
        }
    }

#pragma unroll
    for (int i = 0; i < 8; i++) {
        int gr = block_row + tr + i;
        if (gr < M) {
#pragma unroll
            for (int j = 0; j < 8; j += 4) {
                float4 v = make_float4(acc[i][j], acc[i][j+1], acc[i][j+2], acc[i][j+3]);
                *(float4*)(C + (size_t)gr * 128 + tc + j) = v;
            }
        }
    }
}

// ---------------- GEMM: [M,128] @ [128,40] -> [M,40] ----------------

__global__ __launch_bounds__(320) void gemm_f32_40(const float* __restrict__ A,
                                                   const float* __restrict__ B,
                                                   float* __restrict__ C, int M) {
    __shared__ float Ws[128][40];
    __shared__ float Xs[32][132];
    int t = threadIdx.x;
    int block_row = blockIdx.x * 32;

    for (int i = t; i < 128 * 40; i += 320) ((float*)Ws)[i] = B[i];
    for (int idx = t; idx < 1024; idx += 320) {
        int row = idx >> 5;
        int k4  = (idx & 31) << 2;
        int gr = block_row + row; if (gr >= M) gr = M - 1;
        float4 v = *(const float4*)(A + (size_t)gr * 128 + k4);
        *(float4*)&Xs[row][k4] = v;
    }
    __syncthreads();

    int r  = t / 10;
    int c0 = (t % 10) * 4;
    float4 acc = make_float4(0.f, 0.f, 0.f, 0.f);
    for (int k = 0; k < 128; k += 4) {
        float4 xv = *(const float4*)&Xs[r][k];
#pragma unroll
        for (int j = 0; j < 4; j++) {
            float xj = (j == 0) ? xv.x : (j == 1) ? xv.y : (j == 2) ? xv.z : xv.w;
            float4 wv = *(const float4*)&Ws[k + j][c0];
            acc.x += xj * wv.x; acc.y += xj * wv.y;
            acc.z += xj * wv.z; acc.w += xj * wv.w;
        }
    }
    int gr = block_row + r;
    if (gr < M) *(float4*)(C + (size_t)gr * 40 + c0) = acc;
}

// ---------------- CSR aggregation: one wave per node, 4-way unrolled ----------------
// out[i] = relu?( dinv[i] * (dinv[i]*h[i] + sum_s dinv[s]*h[s]) + b )

template <int NF, bool RELU>
__global__ __launch_bounds__(256) void agg_kernel(const float* __restrict__ h,
                                                  const float* __restrict__ dinv,
                                                  const int* __restrict__ offsets,
                                                  const int* __restrict__ srcSorted,
                                                  const float* __restrict__ bias,
                                                  float* __restrict__ out, int n) {
    int wave = threadIdx.x >> 6;
    int lane = threadIdx.x & 63;
    int node = blockIdx.x * 4 + wave;
    if (node >= n) return;

    int f = lane * 2;
    bool act = (f < NF);
    float di = dinv[node];

    float2 a0 = make_float2(0.f, 0.f), a1 = a0, a2 = a0, a3 = a0;
    if (act) {
        float2 hv = *(const float2*)(h + (size_t)node * NF + f);
        a0.x = di * hv.x; a0.y = di * hv.y;
    }

    int beg = offsets[node], end = offsets[node + 1];
    int idx = beg;
    // main: 4 independent gathers in flight
    for (; idx + 4 <= end; idx += 4) {
        int s0 = srcSorted[idx];
        int s1 = srcSorted[idx + 1];
        int s2 = srcSorted[idx + 2];
        int s3 = srcSorted[idx + 3];
        float w0 = dinv[s0], w1 = dinv[s1], w2 = dinv[s2], w3 = dinv[s3];
        if (act) {
            float2 h0 = *(const float2*)(h + (size_t)s0 * NF + f);
            float2 h1 = *(const float2*)(h + (size_t)s1 * NF + f);
            float2 h2 = *(const float2*)(h + (size_t)s2 * NF + f);
            float2 h3 = *(const float2*)(h + (size_t)s3 * NF + f);
            a0.x += w0 * h0.x; a0.y += w0 * h0.y;
            a1.x += w1 * h1.x; a1.y += w1 * h1.y;
            a2.x += w2 * h2.x; a2.y += w2 * h2.y;
            a3.x += w3 * h3.x; a3.y += w3 * h3.y;
        }
    }
    // remainder: 2 then 1
    if (idx + 2 <= end) {
        int s0 = srcSorted[idx];
        int s1 = srcSorted[idx + 1];
        float w0 = dinv[s0], w1 = dinv[s1];
        if (act) {
            float2 h0 = *(const float2*)(h + (size_t)s0 * NF + f);
            float2 h1 = *(const float2*)(h + (size_t)s1 * NF + f);
            a0.x += w0 * h0.x; a0.y += w0 * h0.y;
            a1.x += w1 * h1.x; a1.y += w1 * h1.y;
        }
        idx += 2;
    }
    if (idx < end) {
        int s0 = srcSorted[idx];
        float w0 = dinv[s0];
        if (act) {
            float2 h0 = *(const float2*)(h + (size_t)s0 * NF + f);
            a2.x += w0 * h0.x; a2.y += w0 * h0.y;
        }
    }

    if (act) {
        float2 o;
        o.x = di * ((a0.x + a1.x) + (a2.x + a3.x)) + bias[f];
        o.y = di * ((a0.y + a1.y) + (a2.y + a3.y)) + bias[f + 1];
        if (RELU) { o.x = fmaxf(o.x, 0.f); o.y = fmaxf(o.y, 0.f); }
        *(float2*)(out + (size_t)node * NF + f) = o;
    }
}

// ---------------- orchestration ----------------

extern "C" void kernel_launch(void* const* d_in, const int* in_sizes, int n_in,
                              void* d_out, int out_size, void* d_ws, size_t ws_size,
                              hipStream_t stream) {
    const float* x  = (const float*)d_in[0];
    const int* edge = (const int*)d_in[1];
    const float* W1 = (const float*)d_in[2]; const float* b1 = (const float*)d_in[3];
    const float* W2 = (const float*)d_in[4]; const float* b2 = (const float*)d_in[5];
    const float* W3 = (const float*)d_in[6]; const float* b3 = (const float*)d_in[7];
    const float* W4 = (const float*)d_in[8]; const float* b4 = (const float*)d_in[9];

    const int N = in_sizes[0] / 128;      // 100000
    const int E = in_sizes[1] / 2;        // 1600000
    const int* src = edge;
    const int* dst = edge + E;

    float* out_final = (float*)d_out;                    // [N,40]
    float* x_latent  = (float*)d_out + (size_t)N * 40;   // [N,128]

    // workspace carve-up
    char* w = (char*)d_ws;
    int* counts    = (int*)w;  w += (size_t)N * 4;
    int* cursor    = (int*)w;  w += (size_t)N * 4;
    int* offsets   = (int*)w;  w += (size_t)(N + 4) * 4;
    float* dinv    = (float*)w; w += (size_t)N * 4;
    int* srcSorted = (int*)w;  w += (size_t)E * 4;
    int* blockSums = (int*)w;  w += (size_t)1024 * 4;
    w = (char*)(((uintptr_t)w + 255) & ~(uintptr_t)255);
    float* hA = (float*)w; w += (size_t)N * 128 * 4;
    float* hB = (float*)w; w += (size_t)N * 128 * 4;

    int gN = (N + 255) / 256;
    int gE = (E + 255) / 256;
    int nb = (N + 1023) / 1024;   // 98 scan blocks

    init_counts<<<gN, 256, 0, stream>>>(counts, cursor, N);
    count_edges<<<gE, 256, 0, stream>>>(dst, counts, E);
    compute_dinv<<<gN, 256, 0, stream>>>(counts, dinv, N);
    scan_phase1<<<nb, 256, 0, stream>>>(counts, blockSums, N);
    scan_phase2<<<1, 1024, 0, stream>>>(blockSums, nb);
    scan_phase3<<<nb, 256, 0, stream>>>(counts, blockSums, offsets, N, E);
    scatter_edges<<<gE, 256, 0, stream>>>(src, dst, offsets, cursor, srcSorted, E);

    int gGemm = (N + 127) / 128;   // 782
    int gAgg  = (N + 3) / 4;       // 25000

    gemm_f32_128<<<gGemm, 256, 0, stream>>>(x, W1, hA, N);
    agg_kernel<128, true><<<gAgg, 256, 0, stream>>>(hA, dinv, offsets, srcSorted, b1, hB, N);
    gemm_f32_128<<<gGemm, 256, 0, stream>>>(hB, W2, hA, N);
    agg_kernel<128, true><<<gAgg, 256, 0, stream>>>(hA, dinv, offsets, srcSorted, b2, hB, N);
    gemm_f32_128<<<gGemm, 256, 0, stream>>>(hB, W3, hA, N);
    agg_kernel<128, true><<<gAgg, 256, 0, stream>>>(hA, dinv, offsets, srcSorted, b3, x_latent, N);
    gemm_f32_40<<<(N + 31) / 32, 320, 0, stream>>>(x_latent, W4, hA, N);
    agg_kernel<40, false><<<gAgg, 256, 0, stream>>>(hA, dinv, offsets, srcSorted, b4, out_final, N);
}